// Round 2
// baseline (262.228 us; speedup 1.0000x reference)
//
#include <hip/hip_runtime.h>
#include <hip/hip_bf16.h>
#include <math.h>
#include <stdint.h>

typedef __bf16 bf16_t;
typedef bf16_t bf16x8 __attribute__((ext_vector_type(8)));
typedef bf16_t bf16x4 __attribute__((ext_vector_type(4)));
typedef float f32x4 __attribute__((ext_vector_type(4)));

#define GLOBAL_AS __attribute__((address_space(1)))
#define LDS_AS __attribute__((address_space(3)))

__device__ __forceinline__ void gload_lds16(const void* g, void* l) {
    __builtin_amdgcn_global_load_lds((const GLOBAL_AS unsigned int*)g,
                                     (LDS_AS unsigned int*)l, 16, 0, 0);
}

__device__ __forceinline__ f32x4 mfma16(bf16x8 a, bf16x8 b, f32x4 c) {
    return __builtin_amdgcn_mfma_f32_16x16x32_bf16(a, b, c, 0, 0, 0);
}

// ---------------------------------------------------------------- LayerNorm
__global__ void ln_kernel(const float* __restrict__ x, const float* __restrict__ g,
                          const float* __restrict__ b, bf16_t* __restrict__ out)
{
    const int row = blockIdx.x;
    const int tid = threadIdx.x;
    const float4 v = ((const float4*)(x + (size_t)row * 1024))[tid];
    float s  = v.x + v.y + v.z + v.w;
    float s2 = v.x * v.x + v.y * v.y + v.z * v.z + v.w * v.w;
    #pragma unroll
    for (int m = 1; m < 64; m <<= 1) {
        s  += __shfl_xor(s, m);
        s2 += __shfl_xor(s2, m);
    }
    __shared__ float red[8];
    const int wid = tid >> 6, lane = tid & 63;
    if (lane == 0) { red[wid] = s; red[4 + wid] = s2; }
    __syncthreads();
    s  = red[0] + red[1] + red[2] + red[3];
    s2 = red[4] + red[5] + red[6] + red[7];
    const float mu  = s * (1.0f / 1024.0f);
    const float var = s2 * (1.0f / 1024.0f) - mu * mu;
    const float rs  = rsqrtf(var + 1e-5f);
    const float4 gv = ((const float4*)g)[tid];
    const float4 bv = ((const float4*)b)[tid];
    bf16x4 o;
    o[0] = (bf16_t)((v.x - mu) * rs * gv.x + bv.x);
    o[1] = (bf16_t)((v.y - mu) * rs * gv.y + bv.y);
    o[2] = (bf16_t)((v.z - mu) * rs * gv.z + bv.z);
    o[3] = (bf16_t)((v.w - mu) * rs * gv.w + bv.w);
    *(bf16x4*)&out[(size_t)row * 1024 + tid * 4] = o;
}

// ---------------------------------------------------------------- fp32 -> bf16
__global__ void cvt_bf16(const float* __restrict__ in, bf16_t* __restrict__ out, int n4)
{
    const int i = blockIdx.x * 256 + threadIdx.x;
    if (i < n4) {
        const float4 v = ((const float4*)in)[i];
        bf16x4 o;
        o[0] = (bf16_t)v.x; o[1] = (bf16_t)v.y; o[2] = (bf16_t)v.z; o[3] = (bf16_t)v.w;
        *(bf16x4*)&out[(size_t)i * 4] = o;
    }
}

// ---------------------------------------------------------------- RoPE tables [1024 pos][64 d] fp32
__global__ void rope_tables(float* __restrict__ cb, float* __restrict__ sb)
{
    const int p = blockIdx.x;
    const int d = threadIdx.x;
    const int hh = p >> 5, ww = p & 31;
    const int idx = d & 15;
    const float invf = powf(10000.0f, -(float)idx / 16.0f);
    const float posv = (d >= 32) ? (float)hh : (float)ww;
    const float f = posv * invf;
    cb[p * 64 + d] = cosf(f);
    sb[p * 64 + d] = sinf(f);
}

// ---------------------------------------------------------------- GEMM C = A(bf16,[M][K]) * B(bf16,[N][K])^T
// EPI 0: fused RoPE epilogue -> Qb/Kb, V scattered transposed -> Vt.  EPI 1: fp32 to Cout.
template <int EPI>
__global__ __launch_bounds__(256, 2)
void gemm_bt(const bf16_t* __restrict__ A, const bf16_t* __restrict__ Bw,
             int M, int N, int K,
             bf16_t* __restrict__ Qb, bf16_t* __restrict__ Kb, bf16_t* __restrict__ Vt,
             const float* __restrict__ cb, const float* __restrict__ sb,
             float* __restrict__ Cout)
{
    __shared__ bf16_t Asm[128 * 64];
    __shared__ bf16_t Bsm[128 * 64];
    const int tid  = threadIdx.x;
    const int lane = tid & 63;
    const int wid  = tid >> 6;
    const int wr = wid >> 1, wc = wid & 1;

    // XCD-aware swizzle (nwg % 8 == 0 for both instantiations)
    int lin = blockIdx.y * gridDim.x + blockIdx.x;
    const int cpx = (gridDim.x * gridDim.y) >> 3;
    lin = (lin & 7) * cpx + (lin >> 3);
    const int bx = lin % gridDim.x;
    const int by = lin / gridDim.x;
    const int bm = by * 128;
    const int bn = bx * 128;

    f32x4 acc[4][4] = {};

    const int r0  = tid >> 3;
    const int ke0 = (tid & 7) * 8;

    for (int k0 = 0; k0 < K; k0 += 64) {
        __syncthreads();
        #pragma unroll
        for (int i = 0; i < 4; ++i) {
            gload_lds16(A  + (size_t)(bm + r0 + i * 32) * K + k0 + ke0, (char*)Asm + i * 4096 + tid * 16);
            gload_lds16(Bw + (size_t)(bn + r0 + i * 32) * K + k0 + ke0, (char*)Bsm + i * 4096 + tid * 16);
        }
        __syncthreads();
        #pragma unroll
        for (int kk = 0; kk < 2; ++kk) {
            bf16x8 af[4], bv[4];
            #pragma unroll
            for (int mi = 0; mi < 4; ++mi)
                af[mi] = *(const bf16x8*)&Asm[(wr * 64 + mi * 16 + (lane & 15)) * 64 + kk * 32 + (lane >> 4) * 8];
            #pragma unroll
            for (int nj = 0; nj < 4; ++nj)
                bv[nj] = *(const bf16x8*)&Bsm[(wc * 64 + nj * 16 + (lane & 15)) * 64 + kk * 32 + (lane >> 4) * 8];
            #pragma unroll
            for (int mi = 0; mi < 4; ++mi)
                #pragma unroll
                for (int nj = 0; nj < 4; ++nj)
                    acc[mi][nj] = mfma16(af[mi], bv[nj], acc[mi][nj]);
        }
    }

    if (EPI == 0) {
        const int sel = bn >> 10;   // uniform per block (128-wide tiles)
        if (sel < 2) {
            bf16_t* dst = sel ? Kb : Qb;
            const float qs = sel ? 1.0f : 0.125f;
            #pragma unroll
            for (int mi = 0; mi < 4; ++mi) {
                #pragma unroll
                for (int nj = 0; nj < 2; ++nj) {
                    #pragma unroll
                    for (int r = 0; r < 4; ++r) {
                        const int m = bm + wr * 64 + mi * 16 + (lane >> 4) * 4 + r;
                        const int n_lo = bn + wc * 64 + nj * 16 + (lane & 15);
                        const int head = (n_lo >> 6) & 15;
                        const int d_lo = nj * 16 + (lane & 15);     // 0..31
                        const int pos  = m & 1023;
                        const int bfi  = m >> 10;
                        const float v_lo = acc[mi][nj][r];
                        const float v_hi = acc[mi][nj + 2][r];
                        const float c_lo = cb[pos * 64 + d_lo],      s_lo = sb[pos * 64 + d_lo];
                        const float c_hi = cb[pos * 64 + d_lo + 32], s_hi = sb[pos * 64 + d_lo + 32];
                        const size_t idx = (((size_t)(bfi * 16 + head)) << 16) + (size_t)pos * 64 + d_lo;
                        dst[idx]      = (bf16_t)((v_lo * c_lo - v_hi * s_lo) * qs);
                        dst[idx + 32] = (bf16_t)((v_hi * c_hi + v_lo * s_hi) * qs);
                    }
                }
            }
        } else {
            // V: scatter directly into transposed layout Vt[bh][d][pos]
            #pragma unroll
            for (int mi = 0; mi < 4; ++mi) {
                #pragma unroll
                for (int nj = 0; nj < 4; ++nj) {
                    #pragma unroll
                    for (int r = 0; r < 4; ++r) {
                        const int m = bm + wr * 64 + mi * 16 + (lane >> 4) * 4 + r;
                        const int n = bn + wc * 64 + nj * 16 + (lane & 15);
                        const int head = (n >> 6) & 15;
                        const int d    = n & 63;
                        const int pos  = m & 1023;
                        const int bfi  = m >> 10;
                        Vt[(((size_t)(bfi * 16 + head)) << 16) + (size_t)d * 1024 + pos] = (bf16_t)acc[mi][nj][r];
                    }
                }
            }
        }
    } else {
        #pragma unroll
        for (int mi = 0; mi < 4; ++mi)
            #pragma unroll
            for (int nj = 0; nj < 4; ++nj)
                #pragma unroll
                for (int r = 0; r < 4; ++r) {
                    const int m = bm + wr * 64 + mi * 16 + (lane >> 4) * 4 + r;
                    const int n = bn + wc * 64 + nj * 16 + (lane & 15);
                    Cout[(size_t)m * N + n] = acc[mi][nj][r];
                }
    }
}

// ---------------------------------------------------------------- flash attention, no K/V staging
// grid 1024 blocks (XCD-swizzled onto (qt, bh)); block 256 = 4 waves x 32 q-rows; K/V read direct from L1/L2
__global__ __launch_bounds__(256, 3)
void attn_kernel(const bf16_t* __restrict__ Q, const bf16_t* __restrict__ Kg,
                 const bf16_t* __restrict__ Vt, bf16_t* __restrict__ AO)
{
    const int lin = blockIdx.x;
    const int bh  = (lin & 7) * 16 + ((lin >> 3) & 15);   // 16 bh per XCD
    const int qt  = lin >> 7;                             // 8 q-tiles
    const int tid = threadIdx.x;
    const int lane = tid & 63;
    const int wid  = tid >> 6;
    const int lr = lane & 15;
    const int lg = lane >> 4;

    __shared__ bf16_t Psm[4][32 * 72];

    const size_t hb = (size_t)bh << 16;
    const bf16_t* Qp = Q  + hb;
    const bf16_t* Kp = Kg + hb;
    const bf16_t* Vp = Vt + hb;

    bf16x8 qf[2][2];
    #pragma unroll
    for (int qtl = 0; qtl < 2; ++qtl)
        #pragma unroll
        for (int kk = 0; kk < 2; ++kk)
            qf[qtl][kk] = *(const bf16x8*)&Qp[(size_t)(qt * 128 + wid * 32 + qtl * 16 + lr) * 64 + kk * 32 + lg * 8];

    f32x4 o[2][4] = {};
    float mrow[2][4], lrow[2][4];
    #pragma unroll
    for (int a = 0; a < 2; ++a)
        #pragma unroll
        for (int r = 0; r < 4; ++r) { mrow[a][r] = -INFINITY; lrow[a][r] = 0.0f; }

    bf16_t* pw = &Psm[wid][0];

    for (int kt = 0; kt < 16; ++kt) {
        // ---- QK^T, B-fragments straight from global (L1/L2 resident)
        f32x4 s[2][4] = {};
        __builtin_amdgcn_s_setprio(1);
        #pragma unroll
        for (int kk = 0; kk < 2; ++kk) {
            bf16x8 kf[4];
            #pragma unroll
            for (int k4 = 0; k4 < 4; ++k4)
                kf[k4] = *(const bf16x8*)&Kp[(size_t)(kt * 64 + k4 * 16 + lr) * 64 + kk * 32 + lg * 8];
            #pragma unroll
            for (int qtl = 0; qtl < 2; ++qtl)
                #pragma unroll
                for (int k4 = 0; k4 < 4; ++k4)
                    s[qtl][k4] = mfma16(qf[qtl][kk], kf[k4], s[qtl][k4]);
        }
        __builtin_amdgcn_s_setprio(0);

        // ---- issue V fragment loads now; latency hides under softmax VALU
        bf16x8 vf[2][4];
        #pragma unroll
        for (int kk = 0; kk < 2; ++kk)
            #pragma unroll
            for (int dt = 0; dt < 4; ++dt)
                vf[kk][dt] = *(const bf16x8*)&Vp[(size_t)(dt * 16 + lr) * 1024 + kt * 64 + kk * 32 + lg * 8];

        // ---- online softmax (wave-parallel, 16-lane-group reduce)
        #pragma unroll
        for (int qtl = 0; qtl < 2; ++qtl) {
            #pragma unroll
            for (int r = 0; r < 4; ++r) {
                float mx = fmaxf(fmaxf(s[qtl][0][r], s[qtl][1][r]), fmaxf(s[qtl][2][r], s[qtl][3][r]));
                mx = fmaxf(mx, __shfl_xor(mx, 1));
                mx = fmaxf(mx, __shfl_xor(mx, 2));
                mx = fmaxf(mx, __shfl_xor(mx, 4));
                mx = fmaxf(mx, __shfl_xor(mx, 8));
                const float mold = mrow[qtl][r];
                const float mnew = fmaxf(mold, mx);
                const float alpha = __expf(mold - mnew);
                float ps = 0.0f;
                #pragma unroll
                for (int k4 = 0; k4 < 4; ++k4) {
                    const float p = __expf(s[qtl][k4][r] - mnew);
                    s[qtl][k4][r] = p;
                    ps += p;
                }
                ps += __shfl_xor(ps, 1);
                ps += __shfl_xor(ps, 2);
                ps += __shfl_xor(ps, 4);
                ps += __shfl_xor(ps, 8);
                lrow[qtl][r] = lrow[qtl][r] * alpha + ps;
                mrow[qtl][r] = mnew;
                #pragma unroll
                for (int dt = 0; dt < 4; ++dt) o[qtl][dt][r] *= alpha;
            }
        }

        // ---- P through per-wave LDS (layout fix for A-fragment)
        #pragma unroll
        for (int qtl = 0; qtl < 2; ++qtl)
            #pragma unroll
            for (int k4 = 0; k4 < 4; ++k4)
                #pragma unroll
                for (int r = 0; r < 4; ++r)
                    pw[(qtl * 16 + lg * 4 + r) * 72 + k4 * 16 + lr] = (bf16_t)s[qtl][k4][r];

        // ---- PV
        __builtin_amdgcn_s_setprio(1);
        #pragma unroll
        for (int kk = 0; kk < 2; ++kk) {
            bf16x8 pf[2];
            #pragma unroll
            for (int qtl = 0; qtl < 2; ++qtl)
                pf[qtl] = *(const bf16x8*)&pw[(qtl * 16 + lr) * 72 + kk * 32 + lg * 8];
            #pragma unroll
            for (int qtl = 0; qtl < 2; ++qtl)
                #pragma unroll
                for (int dt = 0; dt < 4; ++dt)
                    o[qtl][dt] = mfma16(pf[qtl], vf[kk][dt], o[qtl][dt]);
        }
        __builtin_amdgcn_s_setprio(0);
    }

    const int bfi = bh >> 4;
    const int hh  = bh & 15;
    #pragma unroll
    for (int qtl = 0; qtl < 2; ++qtl) {
        #pragma unroll
        for (int r = 0; r < 4; ++r) {
            const float inv = 1.0f / lrow[qtl][r];
            const int qrow = qt * 128 + wid * 32 + qtl * 16 + lg * 4 + r;
            const size_t mbase = (size_t)(bfi * 1024 + qrow) * 1024 + hh * 64;
            #pragma unroll
            for (int dt = 0; dt < 4; ++dt)
                AO[mbase + dt * 16 + lr] = (bf16_t)(o[qtl][dt][r] * inv);
        }
    }
}

// ----------------------------------------------------------------
extern "C" void kernel_launch(void* const* d_in, const int* in_sizes, int n_in,
                              void* d_out, int out_size, void* d_ws, size_t ws_size,
                              hipStream_t stream)
{
    const float* x     = (const float*)d_in[0];
    const float* w_qkv = (const float*)d_in[1];
    const float* w_out = (const float*)d_in[2];
    const float* ln_g  = (const float*)d_in[3];
    const float* ln_b  = (const float*)d_in[4];

    char* ws = (char*)d_ws;
    // layout (MB offsets): xn 0..16, Q 16..32, K 32..48, AO 48..64, Vt 64..80,
    // wq_bf 80..86, wo_bf 87..89, cos 90, sin 91
    bf16_t* xn  = (bf16_t*)(ws);
    bf16_t* Qb  = (bf16_t*)(ws + ((size_t)16 << 20));
    bf16_t* Kb  = (bf16_t*)(ws + ((size_t)32 << 20));
    bf16_t* AO  = (bf16_t*)(ws + ((size_t)48 << 20));
    bf16_t* Vt  = (bf16_t*)(ws + ((size_t)64 << 20));
    bf16_t* wqb = (bf16_t*)(ws + ((size_t)80 << 20));
    bf16_t* wob = (bf16_t*)(ws + ((size_t)87 << 20));
    float*  cb  = (float*)(ws + ((size_t)90 << 20));
    float*  sb  = (float*)(ws + ((size_t)91 << 20));

    cvt_bf16<<<dim3(3072), dim3(256), 0, stream>>>(w_qkv, wqb, 786432);
    cvt_bf16<<<dim3(1024), dim3(256), 0, stream>>>(w_out, wob, 262144);
    rope_tables<<<dim3(1024), dim3(64), 0, stream>>>(cb, sb);
    ln_kernel<<<dim3(8192), dim3(256), 0, stream>>>(x, ln_g, ln_b, xn);
    gemm_bt<0><<<dim3(24, 64), dim3(256), 0, stream>>>(xn, wqb, 8192, 3072, 1024, Qb, Kb, Vt, cb, sb, nullptr);
    attn_kernel<<<dim3(1024), dim3(256), 0, stream>>>(Qb, Kb, Vt, AO);
    gemm_bt<1><<<dim3(8, 64), dim3(256), 0, stream>>>(AO, wob, 8192, 1024, 1024, nullptr, nullptr, nullptr, nullptr, nullptr, (float*)d_out);

    (void)in_sizes; (void)n_in; (void)out_size; (void)ws_size;
}